// Round 2
// baseline (955.508 us; speedup 1.0000x reference)
//
#include <hip/hip_runtime.h>
#include <cstdint>

typedef __attribute__((ext_vector_type(8))) short bf16x8;
typedef __attribute__((ext_vector_type(4))) float f32x4;
typedef unsigned short u16;
typedef unsigned int u32;

constexpr int D   = 2048;
constexpr int H   = 16;
constexpr int HD  = 128;
constexpr int BATCH = 4;
constexpr int S   = 2048;
constexpr int ROWS = BATCH * S;   // 8192
constexpr int N3D = 3 * D;        // 6144

__device__ __forceinline__ u16 f2bf(float f) {
    union { float f; u32 u; } v; v.f = f;
    u32 r = v.u + 0x7FFFu + ((v.u >> 16) & 1u);
    return (u16)(r >> 16);
}

__device__ __forceinline__ void gld_lds16(const u16* g, u16* l) {
    __builtin_amdgcn_global_load_lds(
        (const __attribute__((address_space(1))) void*)g,
        (__attribute__((address_space(3))) void*)l, 16, 0, 0);
}

// ---------------------------------------------------------------- LayerNorm
__global__ __launch_bounds__(256) void ln_bf16_kernel(
    const float* __restrict__ x, const float* __restrict__ gamma,
    const float* __restrict__ beta, u16* __restrict__ out)
{
    const int row = blockIdx.x;
    const int t = threadIdx.x;
    const float* xr = x + (size_t)row * D;
    float4 a = ((const float4*)xr)[2*t];
    float4 b = ((const float4*)xr)[2*t+1];
    float s  = a.x+a.y+a.z+a.w + b.x+b.y+b.z+b.w;
    float ss = a.x*a.x+a.y*a.y+a.z*a.z+a.w*a.w + b.x*b.x+b.y*b.y+b.z*b.z+b.w*b.w;
    #pragma unroll
    for (int off = 32; off > 0; off >>= 1) {
        s  += __shfl_down(s, off);
        ss += __shfl_down(ss, off);
    }
    __shared__ float red[8];
    const int wave = t >> 6, lane = t & 63;
    if (lane == 0) { red[wave] = s; red[4+wave] = ss; }
    __syncthreads();
    const float mu   = (red[0]+red[1]+red[2]+red[3]) * (1.0f/D);
    const float var  = (red[4]+red[5]+red[6]+red[7]) * (1.0f/D) - mu*mu;
    const float rstd = rsqrtf(var + 1e-5f);
    float4 g0  = ((const float4*)gamma)[2*t];
    float4 g1  = ((const float4*)gamma)[2*t+1];
    float4 be0 = ((const float4*)beta)[2*t];
    float4 be1 = ((const float4*)beta)[2*t+1];
    union { uint4 v; u16 e[8]; } o;
    o.e[0] = f2bf((a.x-mu)*rstd*g0.x + be0.x);
    o.e[1] = f2bf((a.y-mu)*rstd*g0.y + be0.y);
    o.e[2] = f2bf((a.z-mu)*rstd*g0.z + be0.z);
    o.e[3] = f2bf((a.w-mu)*rstd*g0.w + be0.w);
    o.e[4] = f2bf((b.x-mu)*rstd*g1.x + be1.x);
    o.e[5] = f2bf((b.y-mu)*rstd*g1.y + be1.y);
    o.e[6] = f2bf((b.z-mu)*rstd*g1.z + be1.z);
    o.e[7] = f2bf((b.w-mu)*rstd*g1.w + be1.w);
    ((uint4*)(out + (size_t)row*D))[t] = o.v;
}

// ------------------------------------------- transpose + fp32->bf16 weights
__global__ __launch_bounds__(256) void transpose_bf16_kernel(
    const float* __restrict__ in, u16* __restrict__ out, int K, int N)
{
    __shared__ u16 tile[64][65];
    const int tn0 = blockIdx.x * 64;
    const int tk0 = blockIdx.y * 64;
    const int t = threadIdx.x;
    const int tx = t & 63;
    const int ty = t >> 6;
    #pragma unroll
    for (int i = 0; i < 16; i++) {
        int k = ty + i*4;
        tile[k][tx] = f2bf(in[(size_t)(tk0+k)*N + tn0 + tx]);
    }
    __syncthreads();
    #pragma unroll
    for (int i = 0; i < 16; i++) {
        int n = ty + i*4;
        out[(size_t)(tn0+n)*K + tk0 + tx] = tile[tx][n];
    }
}

// ---------------------------------------------------------------- GEMM
// m97 structure: global_load_lds width=16 staging, unpadded LDS [128][32]
constexpr int BM = 128, BN = 128, BK = 32;

template<bool OUT_BF16>
__global__ __launch_bounds__(256) void gemm_bt_kernel(
    const u16* __restrict__ A, const u16* __restrict__ Bt,
    const float* __restrict__ bias, void* __restrict__ Cout,
    int M, int N, int K)
{
    __shared__ u16 sA[BM * BK];   // [128][32] unpadded, 8 KB
    __shared__ u16 sB[BN * BK];
    const int t = threadIdx.x;
    const int wave = t >> 6, lane = t & 63;
    const int lr = lane & 15, lq = lane >> 4;
    const int wm = (wave >> 1) * 64, wn = (wave & 1) * 64;
    const int m0 = blockIdx.y * BM, n0 = blockIdx.x * BN;

    // staging geometry: wave w, instr j -> LDS elems [(w*2+j)*512, +512)
    // lane i covers row w*32 + j*16 + i/4, cols (i&3)*8 .. +8
    const int srow = wave * 32 + (lane >> 2);   // j=0 row
    const int scol = (lane & 3) * 8;
    u16* ldsA0 = sA + (wave*2 + 0) * 512;
    u16* ldsA1 = sA + (wave*2 + 1) * 512;
    u16* ldsB0 = sB + (wave*2 + 0) * 512;
    u16* ldsB1 = sB + (wave*2 + 1) * 512;
    const u16* gA0 = A  + (size_t)(m0 + srow     ) * K + scol;
    const u16* gA1 = A  + (size_t)(m0 + srow + 16) * K + scol;
    const u16* gB0 = Bt + (size_t)(n0 + srow     ) * K + scol;
    const u16* gB1 = Bt + (size_t)(n0 + srow + 16) * K + scol;

    f32x4 acc[4][4];
    #pragma unroll
    for (int i = 0; i < 4; i++)
        #pragma unroll
        for (int j = 0; j < 4; j++)
            acc[i][j] = (f32x4)(0.0f);

    for (int k0 = 0; k0 < K; k0 += BK) {
        __syncthreads();   // previous iteration's LDS reads complete
        gld_lds16(gA0 + k0, ldsA0);
        gld_lds16(gA1 + k0, ldsA1);
        gld_lds16(gB0 + k0, ldsB0);
        gld_lds16(gB1 + k0, ldsB1);
        __syncthreads();   // drains vmcnt(0): staged data visible
        bf16x8 af[4], bfr[4];
        #pragma unroll
        for (int mt = 0; mt < 4; mt++)
            af[mt] = *(const bf16x8*)(sA + (wm + mt*16 + lr) * BK + lq*8);
        #pragma unroll
        for (int nt = 0; nt < 4; nt++)
            bfr[nt] = *(const bf16x8*)(sB + (wn + nt*16 + lr) * BK + lq*8);
        #pragma unroll
        for (int mt = 0; mt < 4; mt++)
            #pragma unroll
            for (int nt = 0; nt < 4; nt++)
                acc[mt][nt] = __builtin_amdgcn_mfma_f32_16x16x32_bf16(
                    af[mt], bfr[nt], acc[mt][nt], 0, 0, 0);
    }

    #pragma unroll
    for (int mt = 0; mt < 4; mt++) {
        #pragma unroll
        for (int nt = 0; nt < 4; nt++) {
            const int col = n0 + wn + nt*16 + lr;
            const float bv = bias[col];
            #pragma unroll
            for (int r = 0; r < 4; r++) {
                const int row = m0 + wm + mt*16 + lq*4 + r;
                const float v = acc[mt][nt][r] + bv;
                if (OUT_BF16)
                    ((u16*)Cout)[(size_t)row * N + col] = f2bf(v);
                else
                    ((float*)Cout)[(size_t)row * N + col] = v;
            }
        }
    }
}

// ---------------------------------------------------------- flash attention
// TQ=128 (32 q-rows per wave), TK=64
constexpr int TQ = 128, TK = 64;
constexpr int KPAD = 136;
constexpr int VPAD = 72;
constexpr int PPAD = 72;

__global__ __launch_bounds__(256) void attn_kernel(
    const u16* __restrict__ qkv, u16* __restrict__ ctx)
{
    __shared__ u16 sK[TK * KPAD];        // [64][136]  17.4 KB
    __shared__ u16 sV[HD * VPAD];        // V^T [128][72]  18.4 KB
    __shared__ u16 sP[4 * 32 * PPAD];    // per-wave P [32][72]  18.4 KB

    const int bh = blockIdx.x;
    const int b  = bh >> 4, h = bh & 15;
    const int qt = blockIdx.y;
    const int q0 = qt * TQ;
    const int t = threadIdx.x;
    const int wave = t >> 6, lane = t & 63;
    const int lr = lane & 15, lq = lane >> 4;

    const u16* base = qkv + (size_t)b * S * N3D + h * HD;

    // Q fragments: 2 M-rows of 16 per wave (rows q0 + wave*32 + mr*16 + lr)
    bf16x8 qf[2][4];
    #pragma unroll
    for (int mr = 0; mr < 2; mr++) {
        const int qrow = q0 + wave*32 + mr*16 + lr;
        #pragma unroll
        for (int kc = 0; kc < 4; kc++)
            qf[mr][kc] = *(const bf16x8*)(base + (size_t)qrow * N3D + kc*32 + lq*8);
    }

    float m_r[2][4], l_r[2][4];
    f32x4 o[2][8];
    #pragma unroll
    for (int mr = 0; mr < 2; mr++) {
        #pragma unroll
        for (int r = 0; r < 4; r++) { m_r[mr][r] = -1e30f; l_r[mr][r] = 0.0f; }
        #pragma unroll
        for (int j = 0; j < 8; j++) o[mr][j] = (f32x4)(0.0f);
    }

    const float scale = 0.08838834764831845f; // 1/sqrt(128)
    const int nkt = 2*qt + 2;

    for (int kt = 0; kt < nkt; kt++) {
        __syncthreads();
        #pragma unroll
        for (int i = 0; i < 4; i++) {
            int c = t + i * 256;
            int krow = c >> 4, kcol = (c & 15) * 8;
            uint4 v = *(const uint4*)(base + D + (size_t)(kt*TK + krow) * N3D + kcol);
            *(uint4*)(sK + krow * KPAD + kcol) = v;
        }
        #pragma unroll
        for (int i = 0; i < 4; i++) {
            int c = t + i * 256;
            int vrow = c & 63, vcol0 = (c >> 6) * 8;
            union { uint4 v; u16 e[8]; } u;
            u.v = *(const uint4*)(base + 2*D + (size_t)(kt*TK + vrow) * N3D + vcol0);
            #pragma unroll
            for (int e = 0; e < 8; e++)
                sV[(vcol0 + e) * VPAD + vrow] = u.e[e];
        }
        __syncthreads();

        // skip compute if this wave's 32 q-rows are all masked for this tile
        if (kt*TK > q0 + wave*32 + 31) continue;

        u16* pw = sP + wave * 32 * PPAD;
        #pragma unroll
        for (int mr = 0; mr < 2; mr++) {
            f32x4 sc[4];
            #pragma unroll
            for (int nt = 0; nt < 4; nt++) sc[nt] = (f32x4)(0.0f);
            #pragma unroll
            for (int nt = 0; nt < 4; nt++)
                #pragma unroll
                for (int kc = 0; kc < 4; kc++) {
                    bf16x8 kf = *(const bf16x8*)(sK + (nt*16 + lr) * KPAD + kc*32 + lq*8);
                    sc[nt] = __builtin_amdgcn_mfma_f32_16x16x32_bf16(qf[mr][kc], kf, sc[nt], 0, 0, 0);
                }

            float rowmax[4] = {-1e30f, -1e30f, -1e30f, -1e30f};
            const int qgb = q0 + wave*32 + mr*16 + lq*4;
            #pragma unroll
            for (int nt = 0; nt < 4; nt++)
                #pragma unroll
                for (int r = 0; r < 4; r++) {
                    float sv = sc[nt][r] * scale;
                    const int kg = kt*TK + nt*16 + lr;
                    if (kg > qgb + r) sv = -1e30f;
                    sc[nt][r] = sv;
                    rowmax[r] = fmaxf(rowmax[r], sv);
                }
            #pragma unroll
            for (int mask = 1; mask < 16; mask <<= 1)
                #pragma unroll
                for (int r = 0; r < 4; r++)
                    rowmax[r] = fmaxf(rowmax[r], __shfl_xor(rowmax[r], mask));

            float alpha[4];
            #pragma unroll
            for (int r = 0; r < 4; r++) {
                float nm = fmaxf(m_r[mr][r], rowmax[r]);
                alpha[r] = __expf(m_r[mr][r] - nm);
                m_r[mr][r] = nm;
            }

            #pragma unroll
            for (int nt = 0; nt < 4; nt++) {
                #pragma unroll
                for (int r = 0; r < 4; r++) {
                    float p = __expf(sc[nt][r] - m_r[mr][r]);
                    sc[nt][r] = p;
                    pw[(mr*16 + lq*4 + r) * PPAD + nt*16 + lr] = f2bf(p);
                }
            }
            #pragma unroll
            for (int r = 0; r < 4; r++) {
                float psum = sc[0][r] + sc[1][r] + sc[2][r] + sc[3][r];
                l_r[mr][r] = l_r[mr][r] * alpha[r] + psum;
            }
            #pragma unroll
            for (int j = 0; j < 8; j++)
                #pragma unroll
                for (int r = 0; r < 4; r++)
                    o[mr][j][r] *= alpha[r];
        }

        // O += P * V  for both M-rows (pw holds both, written above)
        #pragma unroll
        for (int mr = 0; mr < 2; mr++) {
            #pragma unroll
            for (int kc2 = 0; kc2 < 2; kc2++) {
                bf16x8 pa = *(const bf16x8*)(pw + (mr*16 + lr) * PPAD + kc2*32 + lq*8);
                #pragma unroll
                for (int n2 = 0; n2 < 8; n2++) {
                    bf16x8 vb = *(const bf16x8*)(sV + (n2*16 + lr) * VPAD + kc2*32 + lq*8);
                    o[mr][n2] = __builtin_amdgcn_mfma_f32_16x16x32_bf16(pa, vb, o[mr][n2], 0, 0, 0);
                }
            }
        }
    }

    #pragma unroll
    for (int mr = 0; mr < 2; mr++) {
        #pragma unroll
        for (int mask = 1; mask < 16; mask <<= 1)
            #pragma unroll
            for (int r = 0; r < 4; r++)
                l_r[mr][r] += __shfl_xor(l_r[mr][r], mask);
        float inv_l[4];
        #pragma unroll
        for (int r = 0; r < 4; r++) inv_l[r] = 1.0f / l_r[mr][r];
        #pragma unroll
        for (int n2 = 0; n2 < 8; n2++)
            #pragma unroll
            for (int r = 0; r < 4; r++) {
                const int qg = q0 + wave*32 + mr*16 + lq*4 + r;
                const float v = o[mr][n2][r] * inv_l[r];
                ctx[(size_t)(b * S + qg) * D + h * HD + n2*16 + lr] = f2bf(v);
            }
    }
}

// ---------------------------------------------------------------- launcher
extern "C" void kernel_launch(void* const* d_in, const int* in_sizes, int n_in,
                              void* d_out, int out_size, void* d_ws, size_t ws_size,
                              hipStream_t stream) {
    const float* hs    = (const float*)d_in[0];
    const float* gamma = (const float*)d_in[1];
    const float* beta  = (const float*)d_in[2];
    const float* Wqkv  = (const float*)d_in[3];
    const float* bqkv  = (const float*)d_in[4];
    const float* Wproj = (const float*)d_in[5];
    const float* bproj = (const float*)d_in[6];

    char* ws = (char*)d_ws;
    size_t off = 0;
    u16* xb   = (u16*)(ws + off); off += (size_t)ROWS * D * 2;
    u16* wtq  = (u16*)(ws + off); off += (size_t)N3D * D * 2;
    u16* wtp  = (u16*)(ws + off); off += (size_t)D * D * 2;
    u16* qkvb = (u16*)(ws + off); off += (size_t)ROWS * N3D * 2;
    u16* ctxb = (u16*)(ws + off);

    ln_bf16_kernel<<<ROWS, 256, 0, stream>>>(hs, gamma, beta, xb);
    transpose_bf16_kernel<<<dim3(N3D/64, D/64), 256, 0, stream>>>(Wqkv, wtq, D, N3D);
    transpose_bf16_kernel<<<dim3(D/64,   D/64), 256, 0, stream>>>(Wproj, wtp, D, D);
    gemm_bt_kernel<true ><<<dim3(N3D/BN, ROWS/BM), 256, 0, stream>>>(
        xb, wtq, bqkv, qkvb, ROWS, N3D, D);
    attn_kernel<<<dim3(BATCH*H, S/TQ), 256, 0, stream>>>(qkvb, ctxb);
    gemm_bt_kernel<false><<<dim3(D/BN, ROWS/BM), 256, 0, stream>>>(
        ctxb, wtp, bproj, (float*)d_out, ROWS, D, D);
}

// Round 3
// 712.428 us; speedup vs baseline: 1.3412x; 1.3412x over previous
//
#include <hip/hip_runtime.h>
#include <cstdint>

typedef __attribute__((ext_vector_type(8))) short bf16x8;
typedef __attribute__((ext_vector_type(4))) float f32x4;
typedef unsigned short u16;
typedef unsigned int u32;

constexpr int D   = 2048;
constexpr int H   = 16;
constexpr int HD  = 128;
constexpr int BATCH = 4;
constexpr int S   = 2048;
constexpr int ROWS = BATCH * S;   // 8192
constexpr int N3D = 3 * D;        // 6144
constexpr int QKW = 2 * D;        // 4096: width of Q|K buffer

__device__ __forceinline__ u16 f2bf(float f) {
    union { float f; u32 u; } v; v.f = f;
    u32 r = v.u + 0x7FFFu + ((v.u >> 16) & 1u);
    return (u16)(r >> 16);
}

__device__ __forceinline__ void gld_lds16(const u16* g, u16* l) {
    __builtin_amdgcn_global_load_lds(
        (const __attribute__((address_space(1))) void*)g,
        (__attribute__((address_space(3))) void*)l, 16, 0, 0);
}

// ---------------------------------------------------------------- LayerNorm
__global__ __launch_bounds__(256) void ln_bf16_kernel(
    const float* __restrict__ x, const float* __restrict__ gamma,
    const float* __restrict__ beta, u16* __restrict__ out)
{
    const int row = blockIdx.x;
    const int t = threadIdx.x;
    const float* xr = x + (size_t)row * D;
    float4 a = ((const float4*)xr)[2*t];
    float4 b = ((const float4*)xr)[2*t+1];
    float s  = a.x+a.y+a.z+a.w + b.x+b.y+b.z+b.w;
    float ss = a.x*a.x+a.y*a.y+a.z*a.z+a.w*a.w + b.x*b.x+b.y*b.y+b.z*b.z+b.w*b.w;
    #pragma unroll
    for (int off = 32; off > 0; off >>= 1) {
        s  += __shfl_down(s, off);
        ss += __shfl_down(ss, off);
    }
    __shared__ float red[8];
    const int wave = t >> 6, lane = t & 63;
    if (lane == 0) { red[wave] = s; red[4+wave] = ss; }
    __syncthreads();
    const float mu   = (red[0]+red[1]+red[2]+red[3]) * (1.0f/D);
    const float var  = (red[4]+red[5]+red[6]+red[7]) * (1.0f/D) - mu*mu;
    const float rstd = rsqrtf(var + 1e-5f);
    float4 g0  = ((const float4*)gamma)[2*t];
    float4 g1  = ((const float4*)gamma)[2*t+1];
    float4 be0 = ((const float4*)beta)[2*t];
    float4 be1 = ((const float4*)beta)[2*t+1];
    union { uint4 v; u16 e[8]; } o;
    o.e[0] = f2bf((a.x-mu)*rstd*g0.x + be0.x);
    o.e[1] = f2bf((a.y-mu)*rstd*g0.y + be0.y);
    o.e[2] = f2bf((a.z-mu)*rstd*g0.z + be0.z);
    o.e[3] = f2bf((a.w-mu)*rstd*g0.w + be0.w);
    o.e[4] = f2bf((b.x-mu)*rstd*g1.x + be1.x);
    o.e[5] = f2bf((b.y-mu)*rstd*g1.y + be1.y);
    o.e[6] = f2bf((b.z-mu)*rstd*g1.z + be1.z);
    o.e[7] = f2bf((b.w-mu)*rstd*g1.w + be1.w);
    ((uint4*)(out + (size_t)row*D))[t] = o.v;
}

// ------------------------------------------- transpose + fp32->bf16 weights
__global__ __launch_bounds__(256) void transpose_bf16_kernel(
    const float* __restrict__ in, u16* __restrict__ out, int K, int N)
{
    __shared__ u16 tile[64][65];
    const int tn0 = blockIdx.x * 64;
    const int tk0 = blockIdx.y * 64;
    const int t = threadIdx.x;
    const int tx = t & 63;
    const int ty = t >> 6;
    #pragma unroll
    for (int i = 0; i < 16; i++) {
        int k = ty + i*4;
        tile[k][tx] = f2bf(in[(size_t)(tk0+k)*N + tn0 + tx]);
    }
    __syncthreads();
    #pragma unroll
    for (int i = 0; i < 16; i++) {
        int n = ty + i*4;
        out[(size_t)(tn0+n)*K + tk0 + tx] = tile[tx][n];
    }
}

// ---------------------------------------------------------------- GEMM
// MODE 0: fp32 C (proj).  MODE 2: QKV split store — Q|K bf16 to qkb (width
// 4096), V transposed to vtb[bh][hd][s] (bf16), so attention can stage V^T
// with plain b128 copies instead of 32 scalar LDS writes per thread.
constexpr int BM = 128, BN = 128, BK = 32;

template<int MODE>
__global__ __launch_bounds__(256) void gemm_bt_kernel(
    const u16* __restrict__ A, const u16* __restrict__ Bt,
    const float* __restrict__ bias, void* __restrict__ Cout,
    u16* __restrict__ vtb, int M, int N, int K)
{
    __shared__ u16 sA[BM * BK];
    __shared__ u16 sB[BN * BK];
    const int t = threadIdx.x;
    const int wave = t >> 6, lane = t & 63;
    const int lr = lane & 15, lq = lane >> 4;
    const int wm = (wave >> 1) * 64, wn = (wave & 1) * 64;
    const int m0 = blockIdx.y * BM, n0 = blockIdx.x * BN;

    const int srow = wave * 32 + (lane >> 2);
    const int scol = (lane & 3) * 8;
    u16* ldsA0 = sA + (wave*2 + 0) * 512;
    u16* ldsA1 = sA + (wave*2 + 1) * 512;
    u16* ldsB0 = sB + (wave*2 + 0) * 512;
    u16* ldsB1 = sB + (wave*2 + 1) * 512;
    const u16* gA0 = A  + (size_t)(m0 + srow     ) * K + scol;
    const u16* gA1 = A  + (size_t)(m0 + srow + 16) * K + scol;
    const u16* gB0 = Bt + (size_t)(n0 + srow     ) * K + scol;
    const u16* gB1 = Bt + (size_t)(n0 + srow + 16) * K + scol;

    f32x4 acc[4][4];
    #pragma unroll
    for (int i = 0; i < 4; i++)
        #pragma unroll
        for (int j = 0; j < 4; j++)
            acc[i][j] = (f32x4)(0.0f);

    for (int k0 = 0; k0 < K; k0 += BK) {
        __syncthreads();
        gld_lds16(gA0 + k0, ldsA0);
        gld_lds16(gA1 + k0, ldsA1);
        gld_lds16(gB0 + k0, ldsB0);
        gld_lds16(gB1 + k0, ldsB1);
        __syncthreads();
        bf16x8 af[4], bfr[4];
        #pragma unroll
        for (int mt = 0; mt < 4; mt++)
            af[mt] = *(const bf16x8*)(sA + (wm + mt*16 + lr) * BK + lq*8);
        #pragma unroll
        for (int nt = 0; nt < 4; nt++)
            bfr[nt] = *(const bf16x8*)(sB + (wn + nt*16 + lr) * BK + lq*8);
        #pragma unroll
        for (int mt = 0; mt < 4; mt++)
            #pragma unroll
            for (int nt = 0; nt < 4; nt++)
                acc[mt][nt] = __builtin_amdgcn_mfma_f32_16x16x32_bf16(
                    af[mt], bfr[nt], acc[mt][nt], 0, 0, 0);
    }

    #pragma unroll
    for (int mt = 0; mt < 4; mt++) {
        #pragma unroll
        for (int nt = 0; nt < 4; nt++) {
            const int col = n0 + wn + nt*16 + lr;
            const float bv = bias[col];
            const int row0 = m0 + wm + mt*16 + lq*4;
            float v[4];
            #pragma unroll
            for (int r = 0; r < 4; r++) v[r] = acc[mt][nt][r] + bv;
            if (MODE == 0) {
                #pragma unroll
                for (int r = 0; r < 4; r++)
                    ((float*)Cout)[(size_t)(row0 + r) * N + col] = v[r];
            } else {
                if (n0 < QKW) {
                    #pragma unroll
                    for (int r = 0; r < 4; r++)
                        ((u16*)Cout)[(size_t)(row0 + r) * QKW + col] = f2bf(v[r]);
                } else {
                    const int vcol = col - QKW;          // 0..2047
                    const int b = row0 >> 11, s0 = row0 & 2047;
                    ushort4 pk;
                    pk.x = f2bf(v[0]); pk.y = f2bf(v[1]);
                    pk.z = f2bf(v[2]); pk.w = f2bf(v[3]);
                    *(ushort4*)(vtb + ((size_t)(b*H + (vcol >> 7)) * HD
                                       + (vcol & 127)) * S + s0) = pk;
                }
            }
        }
    }
}

// ---------------------------------------------------------- flash attention
// TQ=TK=64, 4 waves x 16 q-rows. qkb: [ROWS][4096] = Q|K. vtb: [64][128][2048].
constexpr int TQ = 64, TK = 64;
constexpr int KPAD = 136;
constexpr int VPAD = 72;
constexpr int PPAD = 72;

__global__ __launch_bounds__(256) void attn_kernel(
    const u16* __restrict__ qkb, const u16* __restrict__ vtb,
    u16* __restrict__ ctx)
{
    __shared__ u16 sK[TK * KPAD];        // [64][136]  17.0 KB
    __shared__ u16 sVT[HD * VPAD];       // [128][72]  18.0 KB
    __shared__ u16 sP[4 * 16 * PPAD];    // per-wave [16][72]  9.0 KB

    // longest-first dispatch: first 64 blocks take qt=31 (most K-tiles)
    const int flat = blockIdx.x;
    const int qt = 31 - (flat >> 6);
    const int bh = flat & 63;
    const int b  = bh >> 4, h = bh & 15;
    const int q0 = qt * TQ;
    const int t = threadIdx.x;
    const int wave = t >> 6, lane = t & 63;
    const int lr = lane & 15, lq = lane >> 4;

    const u16* baseQK = qkb + (size_t)b * S * QKW + h * HD;
    const u16* baseVT = vtb + (size_t)bh * HD * S;

    const int qrow = q0 + wave * 16 + lr;
    bf16x8 qf[4];
    #pragma unroll
    for (int kc = 0; kc < 4; kc++)
        qf[kc] = *(const bf16x8*)(baseQK + (size_t)qrow * QKW + kc*32 + lq*8);

    float m_r[4], l_r[4];
    f32x4 o[8];
    #pragma unroll
    for (int r = 0; r < 4; r++) { m_r[r] = -1e30f; l_r[r] = 0.0f; }
    #pragma unroll
    for (int j = 0; j < 8; j++) o[j] = (f32x4)(0.0f);

    const float scale = 0.08838834764831845f; // 1/sqrt(128)
    const int nkt = qt + 1;

    for (int kt = 0; kt < nkt; kt++) {
        __syncthreads();
        // stage K tile [64][128] (padded rows)
        #pragma unroll
        for (int i = 0; i < 4; i++) {
            int c = t + i * 256;
            int krow = c >> 4, kcol = (c & 15) * 8;
            uint4 v = *(const uint4*)(baseQK + D + (size_t)(kt*TK + krow) * QKW + kcol);
            *(uint4*)(sK + krow * KPAD + kcol) = v;
        }
        // stage V^T tile [128 hd][64 keys] straight from vtb — b128 copies
        #pragma unroll
        for (int i = 0; i < 4; i++) {
            int c = t + i * 256;
            int vrow = c >> 3, coff = (c & 7) * 8;
            uint4 v = *(const uint4*)(baseVT + (size_t)vrow * S + kt*TK + coff);
            *(uint4*)(sVT + vrow * VPAD + coff) = v;
        }
        __syncthreads();

        // S = Q K^T
        f32x4 sc[4];
        #pragma unroll
        for (int nt = 0; nt < 4; nt++) sc[nt] = (f32x4)(0.0f);
        #pragma unroll
        for (int nt = 0; nt < 4; nt++)
            #pragma unroll
            for (int kc = 0; kc < 4; kc++) {
                bf16x8 kf = *(const bf16x8*)(sK + (nt*16 + lr) * KPAD + kc*32 + lq*8);
                sc[nt] = __builtin_amdgcn_mfma_f32_16x16x32_bf16(qf[kc], kf, sc[nt], 0, 0, 0);
            }

        const bool diag = (kt == qt);
        float rowmax[4] = {-1e30f, -1e30f, -1e30f, -1e30f};
        const int qgb = q0 + wave*16 + lq*4;
        #pragma unroll
        for (int nt = 0; nt < 4; nt++)
            #pragma unroll
            for (int r = 0; r < 4; r++) {
                float sv = sc[nt][r] * scale;
                if (diag) {
                    const int kg = kt*TK + nt*16 + lr;
                    if (kg > qgb + r) sv = -1e30f;
                }
                sc[nt][r] = sv;
                rowmax[r] = fmaxf(rowmax[r], sv);
            }
        #pragma unroll
        for (int mask = 1; mask < 16; mask <<= 1)
            #pragma unroll
            for (int r = 0; r < 4; r++)
                rowmax[r] = fmaxf(rowmax[r], __shfl_xor(rowmax[r], mask));

        float alpha[4];
        #pragma unroll
        for (int r = 0; r < 4; r++) {
            float nm = fmaxf(m_r[r], rowmax[r]);
            alpha[r] = __expf(m_r[r] - nm);
            m_r[r] = nm;
        }

        u16* pw = sP + wave * 16 * PPAD;
        #pragma unroll
        for (int nt = 0; nt < 4; nt++) {
            #pragma unroll
            for (int r = 0; r < 4; r++) {
                float p = __expf(sc[nt][r] - m_r[r]);
                sc[nt][r] = p;
                pw[(lq*4 + r) * PPAD + nt*16 + lr] = f2bf(p);
            }
        }
        #pragma unroll
        for (int r = 0; r < 4; r++) {
            float psum = sc[0][r] + sc[1][r] + sc[2][r] + sc[3][r];
            l_r[r] = l_r[r] * alpha[r] + psum;
        }
        #pragma unroll
        for (int j = 0; j < 8; j++)
            #pragma unroll
            for (int r = 0; r < 4; r++)
                o[j][r] *= alpha[r];

        // O += P V
        #pragma unroll
        for (int kc2 = 0; kc2 < 2; kc2++) {
            bf16x8 pa = *(const bf16x8*)(pw + lr * PPAD + kc2*32 + lq*8);
            #pragma unroll
            for (int n2 = 0; n2 < 8; n2++) {
                bf16x8 vb = *(const bf16x8*)(sVT + (n2*16 + lr) * VPAD + kc2*32 + lq*8);
                o[n2] = __builtin_amdgcn_mfma_f32_16x16x32_bf16(pa, vb, o[n2], 0, 0, 0);
            }
        }
    }

    #pragma unroll
    for (int mask = 1; mask < 16; mask <<= 1)
        #pragma unroll
        for (int r = 0; r < 4; r++)
            l_r[r] += __shfl_xor(l_r[r], mask);
    float inv_l[4];
    #pragma unroll
    for (int r = 0; r < 4; r++) inv_l[r] = 1.0f / l_r[r];
    #pragma unroll
    for (int n2 = 0; n2 < 8; n2++)
        #pragma unroll
        for (int r = 0; r < 4; r++) {
            const int qg = q0 + wave*16 + lq*4 + r;
            const float v = o[n2][r] * inv_l[r];
            ctx[(size_t)(b * S + qg) * D + h * HD + n2*16 + lr] = f2bf(v);
        }
}

// ---------------------------------------------------------------- launcher
extern "C" void kernel_launch(void* const* d_in, const int* in_sizes, int n_in,
                              void* d_out, int out_size, void* d_ws, size_t ws_size,
                              hipStream_t stream) {
    const float* hs    = (const float*)d_in[0];
    const float* gamma = (const float*)d_in[1];
    const float* beta  = (const float*)d_in[2];
    const float* Wqkv  = (const float*)d_in[3];
    const float* bqkv  = (const float*)d_in[4];
    const float* Wproj = (const float*)d_in[5];
    const float* bproj = (const float*)d_in[6];

    char* ws = (char*)d_ws;
    size_t off = 0;
    u16* xb   = (u16*)(ws + off); off += (size_t)ROWS * D * 2;    // 32 MiB
    u16* wtq  = (u16*)(ws + off); off += (size_t)N3D * D * 2;     // 24 MiB
    u16* wtp  = (u16*)(ws + off); off += (size_t)D * D * 2;       //  8 MiB
    u16* qkb  = (u16*)(ws + off); off += (size_t)ROWS * QKW * 2;  // 64 MiB
    u16* vtb  = (u16*)(ws + off); off += (size_t)ROWS * D * 2;    // 32 MiB
    u16* ctxb = (u16*)(ws + off);                                  // 32 MiB

    ln_bf16_kernel<<<ROWS, 256, 0, stream>>>(hs, gamma, beta, xb);
    transpose_bf16_kernel<<<dim3(N3D/64, D/64), 256, 0, stream>>>(Wqkv, wtq, D, N3D);
    transpose_bf16_kernel<<<dim3(D/64,   D/64), 256, 0, stream>>>(Wproj, wtp, D, D);
    gemm_bt_kernel<2><<<dim3(N3D/BN, ROWS/BM), 256, 0, stream>>>(
        xb, wtq, bqkv, qkb, vtb, ROWS, N3D, D);
    attn_kernel<<<dim3((S/TQ) * BATCH * H), 256, 0, stream>>>(qkb, vtb, ctxb);
    gemm_bt_kernel<0><<<dim3(D/BN, ROWS/BM), 256, 0, stream>>>(
        ctxb, wtp, bproj, (float*)d_out, nullptr, ROWS, D, D);
}

// Round 4
// 711.491 us; speedup vs baseline: 1.3430x; 1.0013x over previous
//
#include <hip/hip_runtime.h>
#include <cstdint>

typedef __attribute__((ext_vector_type(8))) short bf16x8;
typedef __attribute__((ext_vector_type(4))) float f32x4;
typedef unsigned short u16;
typedef unsigned int u32;

constexpr int D   = 2048;
constexpr int H   = 16;
constexpr int HD  = 128;
constexpr int BATCH = 4;
constexpr int S   = 2048;
constexpr int ROWS = BATCH * S;   // 8192
constexpr int N3D = 3 * D;        // 6144
constexpr int QKW = 2 * D;        // 4096: width of Q|K buffer

__device__ __forceinline__ u16 f2bf(float f) {
    union { float f; u32 u; } v; v.f = f;
    u32 r = v.u + 0x7FFFu + ((v.u >> 16) & 1u);
    return (u16)(r >> 16);
}

__device__ __forceinline__ void gld_lds16(const u16* g, u16* l) {
    __builtin_amdgcn_global_load_lds(
        (const __attribute__((address_space(1))) void*)g,
        (__attribute__((address_space(3))) void*)l, 16, 0, 0);
}

// ---------------------------------------------------------------- LayerNorm
__global__ __launch_bounds__(256) void ln_bf16_kernel(
    const float* __restrict__ x, const float* __restrict__ gamma,
    const float* __restrict__ beta, u16* __restrict__ out)
{
    const int row = blockIdx.x;
    const int t = threadIdx.x;
    const float* xr = x + (size_t)row * D;
    float4 a = ((const float4*)xr)[2*t];
    float4 b = ((const float4*)xr)[2*t+1];
    float s  = a.x+a.y+a.z+a.w + b.x+b.y+b.z+b.w;
    float ss = a.x*a.x+a.y*a.y+a.z*a.z+a.w*a.w + b.x*b.x+b.y*b.y+b.z*b.z+b.w*b.w;
    #pragma unroll
    for (int off = 32; off > 0; off >>= 1) {
        s  += __shfl_down(s, off);
        ss += __shfl_down(ss, off);
    }
    __shared__ float red[8];
    const int wave = t >> 6, lane = t & 63;
    if (lane == 0) { red[wave] = s; red[4+wave] = ss; }
    __syncthreads();
    const float mu   = (red[0]+red[1]+red[2]+red[3]) * (1.0f/D);
    const float var  = (red[4]+red[5]+red[6]+red[7]) * (1.0f/D) - mu*mu;
    const float rstd = rsqrtf(var + 1e-5f);
    float4 g0  = ((const float4*)gamma)[2*t];
    float4 g1  = ((const float4*)gamma)[2*t+1];
    float4 be0 = ((const float4*)beta)[2*t];
    float4 be1 = ((const float4*)beta)[2*t+1];
    union { uint4 v; u16 e[8]; } o;
    o.e[0] = f2bf((a.x-mu)*rstd*g0.x + be0.x);
    o.e[1] = f2bf((a.y-mu)*rstd*g0.y + be0.y);
    o.e[2] = f2bf((a.z-mu)*rstd*g0.z + be0.z);
    o.e[3] = f2bf((a.w-mu)*rstd*g0.w + be0.w);
    o.e[4] = f2bf((b.x-mu)*rstd*g1.x + be1.x);
    o.e[5] = f2bf((b.y-mu)*rstd*g1.y + be1.y);
    o.e[6] = f2bf((b.z-mu)*rstd*g1.z + be1.z);
    o.e[7] = f2bf((b.w-mu)*rstd*g1.w + be1.w);
    ((uint4*)(out + (size_t)row*D))[t] = o.v;
}

// ------------------------------------------- transpose + fp32->bf16 weights
__global__ __launch_bounds__(256) void transpose_bf16_kernel(
    const float* __restrict__ in, u16* __restrict__ out, int K, int N)
{
    __shared__ u16 tile[64][65];
    const int tn0 = blockIdx.x * 64;
    const int tk0 = blockIdx.y * 64;
    const int t = threadIdx.x;
    const int tx = t & 63;
    const int ty = t >> 6;
    #pragma unroll
    for (int i = 0; i < 16; i++) {
        int k = ty + i*4;
        tile[k][tx] = f2bf(in[(size_t)(tk0+k)*N + tn0 + tx]);
    }
    __syncthreads();
    #pragma unroll
    for (int i = 0; i < 16; i++) {
        int n = ty + i*4;
        out[(size_t)(tn0+n)*K + tk0 + tx] = tile[tx][n];
    }
}

// ---------------------------------------------------------------- GEMM
// m97 structure + XOR-swizzled LDS staging to kill 8-way bank conflicts.
// LDS[row][blk] = global[row][blk ^ ((row>>1)&3)] (blk = 8-elem col block).
// MODE 0: fp32 C (proj). MODE 2: QKV split store (Q|K bf16; V transposed).
constexpr int BM = 128, BN = 128, BK = 32;

template<int MODE>
__global__ __launch_bounds__(256) void gemm_bt_kernel(
    const u16* __restrict__ A, const u16* __restrict__ Bt,
    const float* __restrict__ bias, void* __restrict__ Cout,
    u16* __restrict__ vtb, int M, int N, int K)
{
    __shared__ u16 sA[BM * BK];
    __shared__ u16 sB[BN * BK];
    const int t = threadIdx.x;
    const int wave = t >> 6, lane = t & 63;
    const int lr = lane & 15, lq = lane >> 4;
    const int wm = (wave >> 1) * 64, wn = (wave & 1) * 64;
    const int m0 = blockIdx.y * BM, n0 = blockIdx.x * BN;

    // staging: lane i covers local row wave*32 + j*16 + (i>>2); its global
    // col-block is (i&3) ^ ((i>>3)&3)  (the XOR swizzle; (row>>1)&3 == (i>>3)&3)
    const int srow = wave * 32 + (lane >> 2);
    const int scb  = (lane & 3) ^ ((lane >> 3) & 3);
    const int scol = scb * 8;
    u16* ldsA0 = sA + (wave*2 + 0) * 512;
    u16* ldsA1 = sA + (wave*2 + 1) * 512;
    u16* ldsB0 = sB + (wave*2 + 0) * 512;
    u16* ldsB1 = sB + (wave*2 + 1) * 512;
    const u16* gA0 = A  + (size_t)(m0 + srow     ) * K + scol;
    const u16* gA1 = A  + (size_t)(m0 + srow + 16) * K + scol;
    const u16* gB0 = Bt + (size_t)(n0 + srow     ) * K + scol;
    const u16* gB1 = Bt + (size_t)(n0 + srow + 16) * K + scol;

    // fragment read col-block for row (..+lr), wanted global block lq:
    const int rblk = (lq ^ ((lr >> 1) & 3)) * 8;

    f32x4 acc[4][4];
    #pragma unroll
    for (int i = 0; i < 4; i++)
        #pragma unroll
        for (int j = 0; j < 4; j++)
            acc[i][j] = (f32x4)(0.0f);

    for (int k0 = 0; k0 < K; k0 += BK) {
        __syncthreads();
        gld_lds16(gA0 + k0, ldsA0);
        gld_lds16(gA1 + k0, ldsA1);
        gld_lds16(gB0 + k0, ldsB0);
        gld_lds16(gB1 + k0, ldsB1);
        __syncthreads();
        bf16x8 af[4], bfr[4];
        #pragma unroll
        for (int mt = 0; mt < 4; mt++)
            af[mt] = *(const bf16x8*)(sA + (wm + mt*16 + lr) * BK + rblk);
        #pragma unroll
        for (int nt = 0; nt < 4; nt++)
            bfr[nt] = *(const bf16x8*)(sB + (wn + nt*16 + lr) * BK + rblk);
        #pragma unroll
        for (int mt = 0; mt < 4; mt++)
            #pragma unroll
            for (int nt = 0; nt < 4; nt++)
                acc[mt][nt] = __builtin_amdgcn_mfma_f32_16x16x32_bf16(
                    af[mt], bfr[nt], acc[mt][nt], 0, 0, 0);
    }

    #pragma unroll
    for (int mt = 0; mt < 4; mt++) {
        #pragma unroll
        for (int nt = 0; nt < 4; nt++) {
            const int col = n0 + wn + nt*16 + lr;
            const float bv = bias[col];
            const int row0 = m0 + wm + mt*16 + lq*4;
            float v[4];
            #pragma unroll
            for (int r = 0; r < 4; r++) v[r] = acc[mt][nt][r] + bv;
            if (MODE == 0) {
                #pragma unroll
                for (int r = 0; r < 4; r++)
                    ((float*)Cout)[(size_t)(row0 + r) * N + col] = v[r];
            } else {
                if (n0 < QKW) {
                    #pragma unroll
                    for (int r = 0; r < 4; r++)
                        ((u16*)Cout)[(size_t)(row0 + r) * QKW + col] = f2bf(v[r]);
                } else {
                    const int vcol = col - QKW;          // 0..2047
                    const int b = row0 >> 11, s0 = row0 & 2047;
                    ushort4 pk;
                    pk.x = f2bf(v[0]); pk.y = f2bf(v[1]);
                    pk.z = f2bf(v[2]); pk.w = f2bf(v[3]);
                    *(ushort4*)(vtb + ((size_t)(b*H + (vcol >> 7)) * HD
                                       + (vcol & 127)) * S + s0) = pk;
                }
            }
        }
    }
}

// ---------------------------------------------------------- flash attention
constexpr int TQ = 64, TK = 64;
constexpr int KPAD = 136;
constexpr int VPAD = 72;
constexpr int PPAD = 72;

__global__ __launch_bounds__(256) void attn_kernel(
    const u16* __restrict__ qkb, const u16* __restrict__ vtb,
    u16* __restrict__ ctx)
{
    __shared__ u16 sK[TK * KPAD];
    __shared__ u16 sVT[HD * VPAD];
    __shared__ u16 sP[4 * 16 * PPAD];

    const int flat = blockIdx.x;
    const int qt = 31 - (flat >> 6);
    const int bh = flat & 63;
    const int b  = bh >> 4, h = bh & 15;
    const int q0 = qt * TQ;
    const int t = threadIdx.x;
    const int wave = t >> 6, lane = t & 63;
    const int lr = lane & 15, lq = lane >> 4;

    const u16* baseQK = qkb + (size_t)b * S * QKW + h * HD;
    const u16* baseVT = vtb + (size_t)bh * HD * S;

    const int qrow = q0 + wave * 16 + lr;
    bf16x8 qf[4];
    #pragma unroll
    for (int kc = 0; kc < 4; kc++)
        qf[kc] = *(const bf16x8*)(baseQK + (size_t)qrow * QKW + kc*32 + lq*8);

    float m_r[4], l_r[4];
    f32x4 o[8];
    #pragma unroll
    for (int r = 0; r < 4; r++) { m_r[r] = -1e30f; l_r[r] = 0.0f; }
    #pragma unroll
    for (int j = 0; j < 8; j++) o[j] = (f32x4)(0.0f);

    const float scale = 0.08838834764831845f; // 1/sqrt(128)
    const int nkt = qt + 1;

    for (int kt = 0; kt < nkt; kt++) {
        __syncthreads();
        #pragma unroll
        for (int i = 0; i < 4; i++) {
            int c = t + i * 256;
            int krow = c >> 4, kcol = (c & 15) * 8;
            uint4 v = *(const uint4*)(baseQK + D + (size_t)(kt*TK + krow) * QKW + kcol);
            *(uint4*)(sK + krow * KPAD + kcol) = v;
        }
        #pragma unroll
        for (int i = 0; i < 4; i++) {
            int c = t + i * 256;
            int vrow = c >> 3, coff = (c & 7) * 8;
            uint4 v = *(const uint4*)(baseVT + (size_t)vrow * S + kt*TK + coff);
            *(uint4*)(sVT + vrow * VPAD + coff) = v;
        }
        __syncthreads();

        f32x4 sc[4];
        #pragma unroll
        for (int nt = 0; nt < 4; nt++) sc[nt] = (f32x4)(0.0f);
        #pragma unroll
        for (int nt = 0; nt < 4; nt++)
            #pragma unroll
            for (int kc = 0; kc < 4; kc++) {
                bf16x8 kf = *(const bf16x8*)(sK + (nt*16 + lr) * KPAD + kc*32 + lq*8);
                sc[nt] = __builtin_amdgcn_mfma_f32_16x16x32_bf16(qf[kc], kf, sc[nt], 0, 0, 0);
            }

        const bool diag = (kt == qt);
        float rowmax[4] = {-1e30f, -1e30f, -1e30f, -1e30f};
        const int qgb = q0 + wave*16 + lq*4;
        #pragma unroll
        for (int nt = 0; nt < 4; nt++)
            #pragma unroll
            for (int r = 0; r < 4; r++) {
                float sv = sc[nt][r] * scale;
                if (diag) {
                    const int kg = kt*TK + nt*16 + lr;
                    if (kg > qgb + r) sv = -1e30f;
                }
                sc[nt][r] = sv;
                rowmax[r] = fmaxf(rowmax[r], sv);
            }
        #pragma unroll
        for (int mask = 1; mask < 16; mask <<= 1)
            #pragma unroll
            for (int r = 0; r < 4; r++)
                rowmax[r] = fmaxf(rowmax[r], __shfl_xor(rowmax[r], mask));

        float alpha[4];
        #pragma unroll
        for (int r = 0; r < 4; r++) {
            float nm = fmaxf(m_r[r], rowmax[r]);
            alpha[r] = __expf(m_r[r] - nm);
            m_r[r] = nm;
        }

        u16* pw = sP + wave * 16 * PPAD;
        #pragma unroll
        for (int nt = 0; nt < 4; nt++) {
            #pragma unroll
            for (int r = 0; r < 4; r++) {
                float p = __expf(sc[nt][r] - m_r[r]);
                sc[nt][r] = p;
                pw[(lq*4 + r) * PPAD + nt*16 + lr] = f2bf(p);
            }
        }
        #pragma unroll
        for (int r = 0; r < 4; r++) {
            float psum = sc[0][r] + sc[1][r] + sc[2][r] + sc[3][r];
            l_r[r] = l_r[r] * alpha[r] + psum;
        }
        #pragma unroll
        for (int j = 0; j < 8; j++)
            #pragma unroll
            for (int r = 0; r < 4; r++)
                o[j][r] *= alpha[r];

        #pragma unroll
        for (int kc2 = 0; kc2 < 2; kc2++) {
            bf16x8 pa = *(const bf16x8*)(pw + lr * PPAD + kc2*32 + lq*8);
            #pragma unroll
            for (int n2 = 0; n2 < 8; n2++) {
                bf16x8 vb = *(const bf16x8*)(sVT + (n2*16 + lr) * VPAD + kc2*32 + lq*8);
                o[n2] = __builtin_amdgcn_mfma_f32_16x16x32_bf16(pa, vb, o[n2], 0, 0, 0);
            }
        }
    }

    #pragma unroll
    for (int mask = 1; mask < 16; mask <<= 1)
        #pragma unroll
        for (int r = 0; r < 4; r++)
            l_r[r] += __shfl_xor(l_r[r], mask);
    float inv_l[4];
    #pragma unroll
    for (int r = 0; r < 4; r++) inv_l[r] = 1.0f / l_r[r];
    #pragma unroll
    for (int n2 = 0; n2 < 8; n2++)
        #pragma unroll
        for (int r = 0; r < 4; r++) {
            const int qg = q0 + wave*16 + lq*4 + r;
            const float v = o[n2][r] * inv_l[r];
            ctx[(size_t)(b * S + qg) * D + h * HD + n2*16 + lr] = f2bf(v);
        }
}

// ---------------------------------------------------------------- launcher
extern "C" void kernel_launch(void* const* d_in, const int* in_sizes, int n_in,
                              void* d_out, int out_size, void* d_ws, size_t ws_size,
                              hipStream_t stream) {
    const float* hs    = (const float*)d_in[0];
    const float* gamma = (const float*)d_in[1];
    const float* beta  = (const float*)d_in[2];
    const float* Wqkv  = (const float*)d_in[3];
    const float* bqkv  = (const float*)d_in[4];
    const float* Wproj = (const float*)d_in[5];
    const float* bproj = (const float*)d_in[6];

    char* ws = (char*)d_ws;
    size_t off = 0;
    u16* xb   = (u16*)(ws + off); off += (size_t)ROWS * D * 2;    // 32 MiB
    u16* wtq  = (u16*)(ws + off); off += (size_t)N3D * D * 2;     // 24 MiB
    u16* wtp  = (u16*)(ws + off); off += (size_t)D * D * 2;       //  8 MiB
    u16* qkb  = (u16*)(ws + off); off += (size_t)ROWS * QKW * 2;  // 64 MiB
    u16* vtb  = (u16*)(ws + off); off += (size_t)ROWS * D * 2;    // 32 MiB
    u16* ctxb = (u16*)(ws + off);                                  // 32 MiB

    ln_bf16_kernel<<<ROWS, 256, 0, stream>>>(hs, gamma, beta, xb);
    transpose_bf16_kernel<<<dim3(N3D/64, D/64), 256, 0, stream>>>(Wqkv, wtq, D, N3D);
    transpose_bf16_kernel<<<dim3(D/64,   D/64), 256, 0, stream>>>(Wproj, wtp, D, D);
    gemm_bt_kernel<2><<<dim3(N3D/BN, ROWS/BM), 256, 0, stream>>>(
        xb, wtq, bqkv, qkb, vtb, ROWS, N3D, D);
    attn_kernel<<<dim3((S/TQ) * BATCH * H), 256, 0, stream>>>(qkb, vtb, ctxb);
    gemm_bt_kernel<0><<<dim3(D/BN, ROWS/BM), 256, 0, stream>>>(
        ctxb, wtp, bproj, (float*)d_out, nullptr, ROWS, D, D);
}